// Round 1
// baseline (536.835 us; speedup 1.0000x reference)
//
#include <hip/hip_runtime.h>

typedef __bf16 bf16_t;
typedef bf16_t bf16x8 __attribute__((ext_vector_type(8)));
typedef float f32x4 __attribute__((ext_vector_type(4)));
typedef unsigned short u16;

#define MFMA16 __builtin_amdgcn_mfma_f32_16x16x32_bf16

#define NT_TOK   12288           // tokens per batch (L*N)
#define T_TOK    49152           // total tokens
#define NWELT    163840          // 160*1024 packed W elements
#define NMELT    196608          // 128*1536 mem elements

// workspace layout (bytes), all 16B aligned
#define WS_PC    0               // float[T_TOK*128]   pc (biased, fp32)
#define WS_S     25165824        // float[T_TOK*24]    seg softmax
#define WS_WB    29884416        // u16[160*1024]      packed seg_w|pc_w bf16
#define WS_MEMF  30212096        // u16[128*1536]      mem bf16 (row-major)
#define WS_MEMT  30605312        // u16[1536*128]      mem^T bf16
#define WS_SKL   30998528        // float[512]         per-(b,f) running max
#define WS_LOSS  31000576        // float[1]

__device__ __forceinline__ u16 f2bf(float f) {
  union { bf16_t h; u16 u; } c; c.h = (bf16_t)f; return c.u;
}

__device__ __forceinline__ void atomic_max_f32(float* a, float v) {
  if (v >= 0.f) atomicMax((int*)a, __float_as_int(v));
  else atomicMin((unsigned int*)a, (unsigned int)__float_as_int(v));
}

// ---------------- init: pack weights/mem to bf16, init reductions ----------
__global__ void k_init(const float* __restrict__ seg_w, const float* __restrict__ pc_w,
                       const float* __restrict__ mem,
                       u16* __restrict__ Wb, u16* __restrict__ memF, u16* __restrict__ memT,
                       float* __restrict__ skl, float* __restrict__ loss)
{
  int i = blockIdx.x * 256 + threadIdx.x;
  if (i < NWELT) {
    int row = i >> 10, k = i & 1023;
    float v = 0.f;
    if (row < 24) v = seg_w[(row << 10) + k];
    else if (row < 152) v = pc_w[((row - 24) << 10) + k];
    Wb[i] = f2bf(v);
  } else if ((i -= NWELT) < NMELT) {
    memF[i] = f2bf(mem[i]);
  } else if ((i -= NMELT) < NMELT) {
    int slot = i >> 7, d = i & 127;
    memT[i] = f2bf(mem[d * 1536 + slot]);
  } else if ((i -= NMELT) < 512) {
    skl[i] = -__builtin_inff();
  } else if (i == 512) {
    *loss = 0.f;
  }
}

// ---------------- projection: [128 tok/block] x 160 cols, bf16 MFMA --------
__global__ __launch_bounds__(256) void k_proj(
    const float* __restrict__ feat, const u16* __restrict__ Wb,
    const float* __restrict__ seg_b, const float* __restrict__ pc_b,
    float* __restrict__ pc_out, float* __restrict__ s_out, float* __restrict__ out_seg)
{
  __shared__ u16 Wl[160 * 32];
  const int tid = threadIdx.x;
  const int w = tid >> 6;
  const int lane = tid & 63;
  const int n = lane & 15;
  const int q = lane >> 4;
  const int base = blockIdx.x * 128;

  f32x4 acc[2][10];
  #pragma unroll
  for (int mi = 0; mi < 2; ++mi)
    #pragma unroll
    for (int t = 0; t < 10; ++t) acc[mi][t] = (f32x4){0.f, 0.f, 0.f, 0.f};

  const uint4* Wg = (const uint4*)Wb;
  uint4* Wl4 = (uint4*)Wl;

  for (int kc = 0; kc < 32; ++kc) {
    const int k0 = kc * 32;
    __syncthreads();
    #pragma unroll
    for (int it = 0; it < 3; ++it) {
      int idx = tid + it * 256;
      if (idx < 640) {
        int row = idx >> 2, c = idx & 3;
        Wl4[idx] = Wg[row * 128 + (k0 >> 3) + c];
      }
    }
    __syncthreads();
    bf16x8 af[2];
    #pragma unroll
    for (int mi = 0; mi < 2; ++mi) {
      const int token = base + w * 32 + mi * 16 + n;
      const float4* fp = (const float4*)(feat + (size_t)token * 1024 + k0 + q * 8);
      float4 x = fp[0], y = fp[1];
      bf16x8 a;
      a[0] = (bf16_t)x.x; a[1] = (bf16_t)x.y; a[2] = (bf16_t)x.z; a[3] = (bf16_t)x.w;
      a[4] = (bf16_t)y.x; a[5] = (bf16_t)y.y; a[6] = (bf16_t)y.z; a[7] = (bf16_t)y.w;
      af[mi] = a;
    }
    #pragma unroll
    for (int t = 0; t < 10; ++t) {
      bf16x8 bfr = *(const bf16x8*)(&Wl[(t * 16 + n) * 32 + q * 8]);
      acc[0][t] = MFMA16(af[0], bfr, acc[0][t], 0, 0, 0);
      acc[1][t] = MFMA16(af[1], bfr, acc[1][t], 0, 0, 0);
    }
  }

  // epilogue: seg softmax (cols 0..23) + biased pc (cols 24..151)
  #pragma unroll
  for (int mi = 0; mi < 2; ++mi) {
    #pragma unroll
    for (int r = 0; r < 4; ++r) {
      const int token = base + w * 32 + mi * 16 + q * 4 + r;
      float v0 = acc[mi][0][r] + seg_b[n];
      float v1 = (n < 8) ? (acc[mi][1][r] + seg_b[16 + n]) : -__builtin_inff();
      float mx = fmaxf(v0, v1);
      #pragma unroll
      for (int d2 = 1; d2 < 16; d2 <<= 1) mx = fmaxf(mx, __shfl_xor(mx, d2, 16));
      float e0 = __expf(v0 - mx);
      float e1 = (n < 8) ? __expf(v1 - mx) : 0.f;
      float sm = e0 + e1;
      #pragma unroll
      for (int d2 = 1; d2 < 16; d2 <<= 1) sm += __shfl_xor(sm, d2, 16);
      float is = 1.f / sm;
      float s0 = e0 * is, s1 = e1 * is;
      s_out[(size_t)token * 24 + n] = s0;
      if (n < 8) s_out[(size_t)token * 24 + 16 + n] = s1;
      const int b = token / NT_TOK;
      const int rem = token - b * NT_TOK;
      const int l = rem >> 9, p = rem & 511;
      float* so = out_seg + ((size_t)(b * 24 + l) * 24) * 512 + p;
      so[(size_t)n * 512] = s0;
      if (n < 8) so[(size_t)(16 + n) * 512] = s1;
      #pragma unroll
      for (int t = 1; t < 10; ++t) {
        int col = t * 16 + n;
        if (col >= 24 && col < 152) {
          pc_out[(size_t)token * 128 + (col - 24)] = acc[mi][t][r] + pc_b[col - 24];
        }
      }
    }
  }
}

// ---------------- attention: flash-style over 24 joint-chunks of 64 slots --
#define SM_S     0
#define SM_STG   12288
#define SM_MF    (12288 + 16384)
#define SM_P     (12288 + 32768)
#define SM_RS    (12288 + 32768 + 16384)
#define SM_RL    (SM_RS + 2048)
#define SM_TOT   (SM_RL + 16)

__global__ __launch_bounds__(256, 2) void k_attn(
    const float* __restrict__ pc, const float* __restrict__ s_in,
    const u16* __restrict__ memF, const u16* __restrict__ memT,
    float* __restrict__ skl, float* __restrict__ loss)
{
  __shared__ __align__(16) char smem[SM_TOT];
  float* s_tile = (float*)(smem + SM_S);        // [128][24]
  u16* Qs  = (u16*)(smem + SM_STG);             // [128][128] (aliases mTl+mFl)
  u16* mTl = (u16*)(smem + SM_STG);             // [64 slots][128 d]
  u16* mFl = (u16*)(smem + SM_MF);              // [128 f][64 slots]
  u16* Pl  = (u16*)(smem + SM_P);               // [128 tok][64 slots]
  float* redS = (float*)(smem + SM_RS);         // [4][128]
  float* redL = (float*)(smem + SM_RL);         // [4]

  const int tid = threadIdx.x;
  const int w = tid >> 6, lane = tid & 63, n = lane & 15, q = lane >> 4;
  const int base = blockIdx.x * 128;

  for (int i = tid; i < 128 * 24; i += 256) s_tile[i] = s_in[(size_t)base * 24 + i];
  {
    const float4* pc4 = (const float4*)(pc + (size_t)base * 128);
    for (int i = tid; i < 4096; i += 256) {
      float4 v = pc4[i];
      ushort4 u;
      u.x = f2bf(v.x); u.y = f2bf(v.y); u.z = f2bf(v.z); u.w = f2bf(v.w);
      *(ushort4*)(&Qs[i * 4]) = u;
    }
  }
  __syncthreads();
  bf16x8 qf[2][4];
  #pragma unroll
  for (int mi = 0; mi < 2; ++mi)
    #pragma unroll
    for (int ks = 0; ks < 4; ++ks)
      qf[mi][ks] = *(const bf16x8*)(&Qs[(w * 32 + mi * 16 + n) * 128 + ks * 32 + q * 8]);
  __syncthreads();

  f32x4 o[2][8];
  #pragma unroll
  for (int mi = 0; mi < 2; ++mi)
    #pragma unroll
    for (int fj = 0; fj < 8; ++fj) o[mi][fj] = (f32x4){0.f, 0.f, 0.f, 0.f};
  float m_run[2][4], l_run[2][4];
  #pragma unroll
  for (int mi = 0; mi < 2; ++mi)
    #pragma unroll
    for (int r = 0; r < 4; ++r) { m_run[mi][r] = -__builtin_inff(); l_run[mi][r] = 0.f; }

  const float invs = 0.088388347648318447f; // 1/sqrt(128)

  for (int j = 0; j < 24; ++j) {
    {
      const uint4* g  = (const uint4*)memT;
      const uint4* g2 = (const uint4*)memF;
      uint4* d4 = (uint4*)mTl;
      uint4* e4 = (uint4*)mFl;
      #pragma unroll
      for (int it = 0; it < 4; ++it) {
        int idx = tid + it * 256;
        d4[idx] = g[(size_t)(j * 64 + (idx >> 4)) * 16 + (idx & 15)];
        e4[idx] = g2[(size_t)(idx >> 3) * 192 + j * 8 + (idx & 7)];
      }
    }
    __syncthreads();

    // S = Q @ mem  (16x16 tiles, Q frags in regs)
    f32x4 sacc[2][4];
    #pragma unroll
    for (int mi = 0; mi < 2; ++mi)
      #pragma unroll
      for (int ni = 0; ni < 4; ++ni) sacc[mi][ni] = (f32x4){0.f, 0.f, 0.f, 0.f};
    #pragma unroll
    for (int ks = 0; ks < 4; ++ks) {
      #pragma unroll
      for (int ni = 0; ni < 4; ++ni) {
        bf16x8 bfr = *(const bf16x8*)(&mTl[(ni * 16 + n) * 128 + ks * 32 + q * 8]);
        sacc[0][ni] = MFMA16(qf[0][ks], bfr, sacc[0][ni], 0, 0, 0);
        sacc[1][ni] = MFMA16(qf[1][ks], bfr, sacc[1][ni], 0, 0, 0);
      }
    }

    // online softmax (scale = s[tok][j]/sqrt(128), constant per chunk)
    #pragma unroll
    for (int mi = 0; mi < 2; ++mi) {
      float lv[4][4], cm[4];
      #pragma unroll
      for (int r = 0; r < 4; ++r) {
        float sj = s_tile[(w * 32 + mi * 16 + q * 4 + r) * 24 + j] * invs;
        #pragma unroll
        for (int ni = 0; ni < 4; ++ni) lv[ni][r] = sacc[mi][ni][r] * sj;
        cm[r] = fmaxf(fmaxf(lv[0][r], lv[1][r]), fmaxf(lv[2][r], lv[3][r]));
      }
      #pragma unroll
      for (int d2 = 1; d2 < 16; d2 <<= 1)
        #pragma unroll
        for (int r = 0; r < 4; ++r) cm[r] = fmaxf(cm[r], __shfl_xor(cm[r], d2, 16));
      float alpha[4], rs[4];
      #pragma unroll
      for (int r = 0; r < 4; ++r) {
        float mnew = fmaxf(m_run[mi][r], cm[r]);
        alpha[r] = __expf(m_run[mi][r] - mnew);
        m_run[mi][r] = mnew;
        rs[r] = 0.f;
      }
      #pragma unroll
      for (int ni = 0; ni < 4; ++ni)
        #pragma unroll
        for (int r = 0; r < 4; ++r) {
          float p = __expf(lv[ni][r] - m_run[mi][r]);
          rs[r] += p;
          Pl[(w * 32 + mi * 16 + q * 4 + r) * 64 + ni * 16 + n] = f2bf(p);
        }
      #pragma unroll
      for (int d2 = 1; d2 < 16; d2 <<= 1)
        #pragma unroll
        for (int r = 0; r < 4; ++r) rs[r] += __shfl_xor(rs[r], d2, 16);
      #pragma unroll
      for (int r = 0; r < 4; ++r) l_run[mi][r] = l_run[mi][r] * alpha[r] + rs[r];
      #pragma unroll
      for (int fj = 0; fj < 8; ++fj)
        #pragma unroll
        for (int r = 0; r < 4; ++r) o[mi][fj][r] *= alpha[r];
    }

    // O += P @ mem^T  (P round-trips LDS: D-layout -> A-layout, per-wave region)
    #pragma unroll
    for (int ks2 = 0; ks2 < 2; ++ks2) {
      bf16x8 pa0 = *(const bf16x8*)(&Pl[(w * 32 + n) * 64 + ks2 * 32 + q * 8]);
      bf16x8 pa1 = *(const bf16x8*)(&Pl[(w * 32 + 16 + n) * 64 + ks2 * 32 + q * 8]);
      #pragma unroll
      for (int fj = 0; fj < 8; ++fj) {
        bf16x8 bfr = *(const bf16x8*)(&mFl[(fj * 16 + n) * 64 + ks2 * 32 + q * 8]);
        o[0][fj] = MFMA16(pa0, bfr, o[0][fj], 0, 0, 0);
        o[1][fj] = MFMA16(pa1, bfr, o[1][fj], 0, 0, 0);
      }
    }
    __syncthreads();
  }

  // finalize: rec = O/l, loss partial, per-f max
  float lsum = 0.f;
  float fmax8[8];
  #pragma unroll
  for (int fj = 0; fj < 8; ++fj) fmax8[fj] = -__builtin_inff();
  #pragma unroll
  for (int mi = 0; mi < 2; ++mi) {
    float linv[4];
    #pragma unroll
    for (int r = 0; r < 4; ++r) linv[r] = 1.f / l_run[mi][r];
    #pragma unroll
    for (int fj = 0; fj < 8; ++fj)
      #pragma unroll
      for (int r = 0; r < 4; ++r) {
        const int token = base + w * 32 + mi * 16 + q * 4 + r;
        float rec = o[mi][fj][r] * linv[r];
        float d = rec - pc[(size_t)token * 128 + fj * 16 + n];
        lsum += d * d;
        fmax8[fj] = fmaxf(fmax8[fj], rec);
      }
  }
  #pragma unroll
  for (int fj = 0; fj < 8; ++fj) {
    float v = fmax8[fj];
    v = fmaxf(v, __shfl_xor(v, 16, 64));
    v = fmaxf(v, __shfl_xor(v, 32, 64));
    fmax8[fj] = v;
  }
  #pragma unroll
  for (int d2 = 1; d2 < 64; d2 <<= 1) lsum += __shfl_xor(lsum, d2, 64);
  if (q == 0) {
    #pragma unroll
    for (int fj = 0; fj < 8; ++fj) redS[w * 128 + fj * 16 + n] = fmax8[fj];
  }
  if (lane == 0) redL[w] = lsum;
  __syncthreads();
  if (tid < 128) {
    float v = fmaxf(fmaxf(redS[tid], redS[128 + tid]), fmaxf(redS[256 + tid], redS[384 + tid]));
    atomic_max_f32(&skl[(base / NT_TOK) * 128 + tid], v);
  }
  if (tid == 0) atomicAdd(loss, redL[0] + redL[1] + redL[2] + redL[3]);
}

// ---------------- head: LN -> Linear -> GELU -> Linear + loss finalize -----
__global__ void k_head(const float* __restrict__ skl,
                       const float* __restrict__ ln_g, const float* __restrict__ ln_b,
                       const float* __restrict__ w1, const float* __restrict__ b1,
                       const float* __restrict__ w2, const float* __restrict__ b2,
                       const float* __restrict__ loss, float* __restrict__ out)
{
  __shared__ float h[128];
  __shared__ float g[64];
  __shared__ float st[2];
  const int t = threadIdx.x;
  for (int b = 0; b < 4; ++b) {
    float x = skl[b * 128 + t];
    h[t] = x;
    __syncthreads();
    if (t == 0) {
      float s = 0.f, ss = 0.f;
      for (int i = 0; i < 128; ++i) { s += h[i]; ss += h[i] * h[i]; }
      float mu = s * (1.f / 128.f);
      st[0] = mu;
      st[1] = ss * (1.f / 128.f) - mu * mu;
    }
    __syncthreads();
    float hn = (x - st[0]) / sqrtf(st[1] + 1e-5f) * ln_g[t] + ln_b[t];
    __syncthreads();
    h[t] = hn;
    __syncthreads();
    if (t < 64) {
      float a = b1[t];
      for (int c = 0; c < 128; ++c) a += h[c] * w1[t * 128 + c];
      g[t] = 0.5f * a * (1.f + erff(a * 0.70710678118654752f));
    }
    __syncthreads();
    if (t < 72) {
      float a = b2[t];
      for (int c = 0; c < 64; ++c) a += g[c] * w2[t * 64 + c];
      out[b * 72 + t] = a;
    }
    __syncthreads();
  }
  if (t == 0) out[1179936] = loss[0] * (1.f / 6291456.f);
}

extern "C" void kernel_launch(void* const* d_in, const int* in_sizes, int n_in,
                              void* d_out, int out_size, void* d_ws, size_t ws_size,
                              hipStream_t stream) {
  (void)in_sizes; (void)n_in; (void)out_size; (void)ws_size;
  const float* feat  = (const float*)d_in[0];
  const float* seg_w = (const float*)d_in[1];
  const float* seg_b = (const float*)d_in[2];
  const float* pc_w  = (const float*)d_in[3];
  const float* pc_b  = (const float*)d_in[4];
  const float* mem   = (const float*)d_in[5];
  const float* ln_g  = (const float*)d_in[6];
  const float* ln_b  = (const float*)d_in[7];
  const float* w1    = (const float*)d_in[8];
  const float* b1    = (const float*)d_in[9];
  const float* w2    = (const float*)d_in[10];
  const float* b2    = (const float*)d_in[11];

  char* ws = (char*)d_ws;
  float* pc_buf = (float*)(ws + WS_PC);
  float* s_buf  = (float*)(ws + WS_S);
  u16*   Wb     = (u16*)(ws + WS_WB);
  u16*   memFb  = (u16*)(ws + WS_MEMF);
  u16*   memTb  = (u16*)(ws + WS_MEMT);
  float* sklb   = (float*)(ws + WS_SKL);
  float* lossb  = (float*)(ws + WS_LOSS);
  float* out    = (float*)d_out;

  k_init<<<2179, 256, 0, stream>>>(seg_w, pc_w, mem, Wb, memFb, memTb, sklb, lossb);
  k_proj<<<384, 256, 0, stream>>>(feat, Wb, seg_b, pc_b, pc_buf, s_buf, out + 288);
  k_attn<<<384, 256, 0, stream>>>(pc_buf, s_buf, memFb, memTb, sklb, lossb);
  k_head<<<1, 128, 0, stream>>>(sklb, ln_g, ln_b, w1, b1, w2, b2, lossb, out);
}

// Round 2
// 465.634 us; speedup vs baseline: 1.1529x; 1.1529x over previous
//
#include <hip/hip_runtime.h>

typedef __bf16 bf16_t;
typedef bf16_t bf16x8 __attribute__((ext_vector_type(8)));
typedef float f32x4 __attribute__((ext_vector_type(4)));
typedef unsigned short u16;

#define MFMA16 __builtin_amdgcn_mfma_f32_16x16x32_bf16

#define NT_TOK   12288           // tokens per batch (L*N)
#define T_TOK    49152           // total tokens
#define NWELT    163840          // 160*1024 packed W elements
#define NMELT    196608          // 128*1536 mem elements

// workspace layout (bytes), all 16B aligned
#define WS_PC    0               // float[T_TOK*128]   pc (biased, fp32)
#define WS_S     25165824        // float[T_TOK*24]    seg softmax
#define WS_WB    29884416        // u16[160*1024]      packed seg_w|pc_w bf16
#define WS_MEMF  30212096        // u16[128*1536]      mem bf16 (row-major)
#define WS_MEMT  30605312        // u16[1536*128]      mem^T bf16
#define WS_SKL   30998528        // float[512]         per-(b,f) running max
#define WS_LOSS  31000576        // float[1]

__device__ __forceinline__ u16 f2bf(float f) {
  union { bf16_t h; u16 u; } c; c.h = (bf16_t)f; return c.u;
}

__device__ __forceinline__ void atomic_max_f32(float* a, float v) {
  if (v >= 0.f) atomicMax((int*)a, __float_as_int(v));
  else atomicMin((unsigned int*)a, (unsigned int)__float_as_int(v));
}

// ---------------- init: pack weights/mem to bf16, init reductions ----------
__global__ void k_init(const float* __restrict__ seg_w, const float* __restrict__ pc_w,
                       const float* __restrict__ mem,
                       u16* __restrict__ Wb, u16* __restrict__ memF, u16* __restrict__ memT,
                       float* __restrict__ skl, float* __restrict__ loss)
{
  int i = blockIdx.x * 256 + threadIdx.x;
  if (i < NWELT) {
    int row = i >> 10, k = i & 1023;
    float v = 0.f;
    if (row < 24) v = seg_w[(row << 10) + k];
    else if (row < 152) v = pc_w[((row - 24) << 10) + k];
    Wb[i] = f2bf(v);
  } else if ((i -= NWELT) < NMELT) {
    memF[i] = f2bf(mem[i]);
  } else if ((i -= NMELT) < NMELT) {
    int slot = i >> 7, d = i & 127;
    memT[i] = f2bf(mem[d * 1536 + slot]);
  } else if ((i -= NMELT) < 512) {
    skl[i] = -__builtin_inff();
  } else if (i == 512) {
    *loss = 0.f;
  }
}

// ---------------- projection: 128 tok/block x 160 cols, no LDS, no barriers
__global__ __launch_bounds__(256, 2) void k_proj(
    const float* __restrict__ feat, const u16* __restrict__ Wb,
    const float* __restrict__ seg_b, const float* __restrict__ pc_b,
    float* __restrict__ pc_out, float* __restrict__ s_out, float* __restrict__ out_seg)
{
  const int tid = threadIdx.x;
  const int w = tid >> 6;
  const int lane = tid & 63;
  const int n = lane & 15;
  const int q = lane >> 4;
  const int base = blockIdx.x * 128;

  f32x4 acc[2][10];
  #pragma unroll
  for (int mi = 0; mi < 2; ++mi)
    #pragma unroll
    for (int t = 0; t < 10; ++t) acc[mi][t] = (f32x4){0.f, 0.f, 0.f, 0.f};

  const int tok0 = base + w * 32 + n;                 // mi=0 token row for this lane
  const float* fp0 = feat + (size_t)tok0 * 1024 + q * 8;
  const float* fp1 = fp0 + 16 * 1024;                 // mi=1 row (+16 tokens)
  const u16* wp = Wb + (size_t)n * 1024 + q * 8;      // row n of t-tile 0; +t*16*1024

  for (int kc = 0; kc < 32; ++kc) {
    const int k0 = kc * 32;
    // W B-frags: direct global (64B-contiguous per 4 q-lanes -> L1-friendly)
    bf16x8 bw[10];
    #pragma unroll
    for (int t = 0; t < 10; ++t)
      bw[t] = *(const bf16x8*)(wp + (size_t)t * 16384 + k0);
    // feat A-frags: 2 float4 per mi, cvt to bf16 in regs
    bf16x8 af[2];
    {
      const float4* a0 = (const float4*)(fp0 + k0);
      const float4* a1 = (const float4*)(fp1 + k0);
      float4 x0 = a0[0], y0 = a0[1];
      float4 x1 = a1[0], y1 = a1[1];
      bf16x8 a;
      a[0] = (bf16_t)x0.x; a[1] = (bf16_t)x0.y; a[2] = (bf16_t)x0.z; a[3] = (bf16_t)x0.w;
      a[4] = (bf16_t)y0.x; a[5] = (bf16_t)y0.y; a[6] = (bf16_t)y0.z; a[7] = (bf16_t)y0.w;
      af[0] = a;
      a[0] = (bf16_t)x1.x; a[1] = (bf16_t)x1.y; a[2] = (bf16_t)x1.z; a[3] = (bf16_t)x1.w;
      a[4] = (bf16_t)y1.x; a[5] = (bf16_t)y1.y; a[6] = (bf16_t)y1.z; a[7] = (bf16_t)y1.w;
      af[1] = a;
    }
    #pragma unroll
    for (int t = 0; t < 10; ++t) {
      acc[0][t] = MFMA16(af[0], bw[t], acc[0][t], 0, 0, 0);
      acc[1][t] = MFMA16(af[1], bw[t], acc[1][t], 0, 0, 0);
    }
  }

  // epilogue: seg softmax (cols 0..23) + biased pc (cols 24..151)
  #pragma unroll
  for (int mi = 0; mi < 2; ++mi) {
    #pragma unroll
    for (int r = 0; r < 4; ++r) {
      const int token = base + w * 32 + mi * 16 + q * 4 + r;
      float v0 = acc[mi][0][r] + seg_b[n];
      float v1 = (n < 8) ? (acc[mi][1][r] + seg_b[16 + n]) : -__builtin_inff();
      float mx = fmaxf(v0, v1);
      #pragma unroll
      for (int d2 = 1; d2 < 16; d2 <<= 1) mx = fmaxf(mx, __shfl_xor(mx, d2, 16));
      float e0 = __expf(v0 - mx);
      float e1 = (n < 8) ? __expf(v1 - mx) : 0.f;
      float sm = e0 + e1;
      #pragma unroll
      for (int d2 = 1; d2 < 16; d2 <<= 1) sm += __shfl_xor(sm, d2, 16);
      float is = 1.f / sm;
      float s0 = e0 * is, s1 = e1 * is;
      s_out[(size_t)token * 24 + n] = s0;
      if (n < 8) s_out[(size_t)token * 24 + 16 + n] = s1;
      const int b = token / NT_TOK;
      const int rem = token - b * NT_TOK;
      const int l = rem >> 9, p = rem & 511;
      float* so = out_seg + ((size_t)(b * 24 + l) * 24) * 512 + p;
      so[(size_t)n * 512] = s0;
      if (n < 8) so[(size_t)(16 + n) * 512] = s1;
      #pragma unroll
      for (int t = 1; t < 10; ++t) {
        int col = t * 16 + n;
        if (col >= 24 && col < 152) {
          pc_out[(size_t)token * 128 + (col - 24)] = acc[mi][t][r] + pc_b[col - 24];
        }
      }
    }
  }
}

// ---------------- attention: S^T layout, padded LDS, wave-private P --------
// LDS offsets (bytes, 16B aligned)
#define AS_S     0                     // float[128][26]  = 13312
#define AS_MT    13312                 // u16[64][136]    = 17408
#define AS_MF    30720                 // u16[128][72]    = 18432
#define AS_P     49152                 // u16[4][32][72]  = 18432 (wave-private)
#define AS_RS    67584                 // float[4][128]   = 2048
#define AS_RL    69632                 // float[4]
#define AS_TOT   69648

__global__ __launch_bounds__(256, 2) void k_attn(
    const float* __restrict__ pc, const float* __restrict__ s_in,
    const u16* __restrict__ memF, const u16* __restrict__ memT,
    float* __restrict__ skl, float* __restrict__ loss)
{
  __shared__ __align__(16) char smem[AS_TOT];
  float* s_tile = (float*)(smem + AS_S);        // [128][26] padded
  u16* mTl = (u16*)(smem + AS_MT);              // [64 slots][136]
  u16* mFl = (u16*)(smem + AS_MF);              // [128 f][72]
  u16* Pl  = (u16*)(smem + AS_P);               // per-wave [32 tok][72]
  float* redS = (float*)(smem + AS_RS);
  float* redL = (float*)(smem + AS_RL);

  const int tid = threadIdx.x;
  const int w = tid >> 6, lane = tid & 63, n = lane & 15, q = lane >> 4;
  const int base = blockIdx.x * 128;
  const int wreg = w * 32 * 72;

  // s tile (padded rows; reads are 4-addr broadcast / conflict-free)
  for (int i = tid; i < 3072; i += 256) {
    int t = i / 24, jj = i - t * 24;
    s_tile[t * 26 + jj] = s_in[(size_t)base * 24 + i];
  }

  // Q fragments straight from global pc (fp32 -> bf16 in regs)
  bf16x8 qf[2][4];
  #pragma unroll
  for (int mt = 0; mt < 2; ++mt)
    #pragma unroll
    for (int ks = 0; ks < 4; ++ks) {
      const float4* qp = (const float4*)(pc + (size_t)(base + w * 32 + mt * 16 + n) * 128 + ks * 32 + q * 8);
      float4 x = qp[0], y = qp[1];
      bf16x8 a;
      a[0] = (bf16_t)x.x; a[1] = (bf16_t)x.y; a[2] = (bf16_t)x.z; a[3] = (bf16_t)x.w;
      a[4] = (bf16_t)y.x; a[5] = (bf16_t)y.y; a[6] = (bf16_t)y.z; a[7] = (bf16_t)y.w;
      qf[mt][ks] = a;
    }

  f32x4 o[2][8];
  #pragma unroll
  for (int mt = 0; mt < 2; ++mt)
    #pragma unroll
    for (int fj = 0; fj < 8; ++fj) o[mt][fj] = (f32x4){0.f, 0.f, 0.f, 0.f};
  float m_run[2] = {-__builtin_inff(), -__builtin_inff()};
  float l_run[2] = {0.f, 0.f};

  const float invs = 0.088388347648318447f; // 1/sqrt(128)

  for (int j = 0; j < 24; ++j) {
    __syncthreads();   // previous iteration's readers done before restage
    {
      const uint4* gT = (const uint4*)memT;
      const uint4* gF = (const uint4*)memF;
      #pragma unroll
      for (int it = 0; it < 4; ++it) {
        int idx = tid + it * 256;
        int slot = idx >> 4, c = idx & 15;
        *(uint4*)(&mTl[slot * 136 + c * 8]) = gT[(size_t)(j * 64 + slot) * 16 + c];
      }
      #pragma unroll
      for (int it = 0; it < 4; ++it) {
        int idx = tid + it * 256;
        int f = idx >> 3, s8 = idx & 7;
        *(uint4*)(&mFl[f * 72 + s8 * 8]) = gF[(size_t)f * 192 + j * 8 + s8];
      }
    }
    __syncthreads();

    // S^T = memChunk . Q^T : A = mT frags (slot rows), B = qf (token cols)
    f32x4 sacc[4][2];
    #pragma unroll
    for (int st = 0; st < 4; ++st) {
      sacc[st][0] = (f32x4){0.f, 0.f, 0.f, 0.f};
      sacc[st][1] = (f32x4){0.f, 0.f, 0.f, 0.f};
    }
    #pragma unroll
    for (int ks = 0; ks < 4; ++ks) {
      #pragma unroll
      for (int st = 0; st < 4; ++st) {
        bf16x8 am = *(const bf16x8*)(&mTl[(st * 16 + n) * 136 + ks * 32 + q * 8]);
        sacc[st][0] = MFMA16(am, qf[0][ks], sacc[st][0], 0, 0, 0);
        sacc[st][1] = MFMA16(am, qf[1][ks], sacc[st][1], 0, 0, 0);
      }
    }

    // online softmax: lane (n,q) holds token n (tile mt), slots st*16+q*4+r
    #pragma unroll
    for (int mt = 0; mt < 2; ++mt) {
      float sj = s_tile[(w * 32 + mt * 16 + n) * 26 + j] * invs;
      float lv[4][4];
      float cm = -__builtin_inff();
      #pragma unroll
      for (int st = 0; st < 4; ++st)
        #pragma unroll
        for (int r = 0; r < 4; ++r) {
          lv[st][r] = sacc[st][mt][r] * sj;
          cm = fmaxf(cm, lv[st][r]);
        }
      cm = fmaxf(cm, __shfl_xor(cm, 16, 64));
      cm = fmaxf(cm, __shfl_xor(cm, 32, 64));
      float mnew = fmaxf(m_run[mt], cm);
      float alpha = __expf(m_run[mt] - mnew);
      m_run[mt] = mnew;
      float rs = 0.f;
      #pragma unroll
      for (int st = 0; st < 4; ++st) {
        float p0 = __expf(lv[st][0] - mnew);
        float p1 = __expf(lv[st][1] - mnew);
        float p2 = __expf(lv[st][2] - mnew);
        float p3 = __expf(lv[st][3] - mnew);
        rs += (p0 + p1) + (p2 + p3);
        ushort4 pk;
        pk.x = f2bf(p0); pk.y = f2bf(p1); pk.z = f2bf(p2); pk.w = f2bf(p3);
        *(ushort4*)(&Pl[wreg + (mt * 16 + n) * 72 + st * 16 + q * 4]) = pk;
      }
      rs += __shfl_xor(rs, 16, 64);
      rs += __shfl_xor(rs, 32, 64);
      l_run[mt] = l_run[mt] * alpha + rs;
      f32x4 av;
      av[0] = __shfl(alpha, q * 4 + 0, 64);
      av[1] = __shfl(alpha, q * 4 + 1, 64);
      av[2] = __shfl(alpha, q * 4 + 2, 64);
      av[3] = __shfl(alpha, q * 4 + 3, 64);
      #pragma unroll
      for (int fj = 0; fj < 8; ++fj) o[mt][fj] *= av;
    }

    // O += P . memF^T (Pl is wave-private: per-wave LDS ops are in order, no barrier)
    #pragma unroll
    for (int h = 0; h < 2; ++h) {
      bf16x8 pa0 = *(const bf16x8*)(&Pl[wreg + n * 72 + h * 32 + q * 8]);
      bf16x8 pa1 = *(const bf16x8*)(&Pl[wreg + (16 + n) * 72 + h * 32 + q * 8]);
      #pragma unroll
      for (int fj = 0; fj < 8; ++fj) {
        bf16x8 bb = *(const bf16x8*)(&mFl[(fj * 16 + n) * 72 + h * 32 + q * 8]);
        o[0][fj] = MFMA16(pa0, bb, o[0][fj], 0, 0, 0);
        o[1][fj] = MFMA16(pa1, bb, o[1][fj], 0, 0, 0);
      }
    }
  }

  // finalize: rec = O/l, loss partial, per-f max
  float lsum = 0.f;
  float fmax8[8];
  #pragma unroll
  for (int fj = 0; fj < 8; ++fj) fmax8[fj] = -__builtin_inff();
  #pragma unroll
  for (int mt = 0; mt < 2; ++mt) {
    f32x4 linv;
    #pragma unroll
    for (int r = 0; r < 4; ++r) linv[r] = 1.f / __shfl(l_run[mt], q * 4 + r, 64);
    #pragma unroll
    for (int fj = 0; fj < 8; ++fj)
      #pragma unroll
      for (int r = 0; r < 4; ++r) {
        const int token = base + w * 32 + mt * 16 + q * 4 + r;
        float rec = o[mt][fj][r] * linv[r];
        float d = rec - pc[(size_t)token * 128 + fj * 16 + n];
        lsum += d * d;
        fmax8[fj] = fmaxf(fmax8[fj], rec);
      }
  }
  #pragma unroll
  for (int fj = 0; fj < 8; ++fj) {
    float v = fmax8[fj];
    v = fmaxf(v, __shfl_xor(v, 16, 64));
    v = fmaxf(v, __shfl_xor(v, 32, 64));
    fmax8[fj] = v;
  }
  #pragma unroll
  for (int d2 = 1; d2 < 64; d2 <<= 1) lsum += __shfl_xor(lsum, d2, 64);
  if (q == 0) {
    #pragma unroll
    for (int fj = 0; fj < 8; ++fj) redS[w * 128 + fj * 16 + n] = fmax8[fj];
  }
  if (lane == 0) redL[w] = lsum;
  __syncthreads();
  if (tid < 128) {
    float v = fmaxf(fmaxf(redS[tid], redS[128 + tid]), fmaxf(redS[256 + tid], redS[384 + tid]));
    atomic_max_f32(&skl[(base / NT_TOK) * 128 + tid], v);
  }
  if (tid == 0) atomicAdd(loss, redL[0] + redL[1] + redL[2] + redL[3]);
}

// ---------------- head: LN -> Linear -> GELU -> Linear + loss finalize -----
__global__ void k_head(const float* __restrict__ skl,
                       const float* __restrict__ ln_g, const float* __restrict__ ln_b,
                       const float* __restrict__ w1, const float* __restrict__ b1,
                       const float* __restrict__ w2, const float* __restrict__ b2,
                       const float* __restrict__ loss, float* __restrict__ out)
{
  __shared__ float hbuf[128];
  __shared__ float gbuf[64];
  __shared__ float red[4];
  const int t = threadIdx.x;            // 128 threads
  const int ln = t & 63, wv = t >> 6;
  for (int b = 0; b < 4; ++b) {
    float x = skl[b * 128 + t];
    float s1 = x, s2 = x * x;
    #pragma unroll
    for (int d = 1; d < 64; d <<= 1) {
      s1 += __shfl_xor(s1, d, 64);
      s2 += __shfl_xor(s2, d, 64);
    }
    if (ln == 0) { red[wv * 2] = s1; red[wv * 2 + 1] = s2; }
    __syncthreads();
    float mu = (red[0] + red[2]) * (1.f / 128.f);
    float var = (red[1] + red[3]) * (1.f / 128.f) - mu * mu;
    float hn = (x - mu) * rsqrtf(var + 1e-5f) * ln_g[t] + ln_b[t];
    hbuf[t] = hn;
    __syncthreads();
    if (t < 64) {
      float a = b1[t];
      for (int c = 0; c < 128; ++c) a += hbuf[c] * w1[t * 128 + c];
      gbuf[t] = 0.5f * a * (1.f + erff(a * 0.70710678118654752f));
    }
    __syncthreads();
    if (t < 72) {
      float a = b2[t];
      for (int c = 0; c < 64; ++c) a += gbuf[c] * w2[t * 64 + c];
      out[b * 72 + t] = a;
    }
    __syncthreads();
  }
  if (t == 0) out[1179936] = loss[0] * (1.f / 6291456.f);
}

extern "C" void kernel_launch(void* const* d_in, const int* in_sizes, int n_in,
                              void* d_out, int out_size, void* d_ws, size_t ws_size,
                              hipStream_t stream) {
  (void)in_sizes; (void)n_in; (void)out_size; (void)ws_size;
  const float* feat  = (const float*)d_in[0];
  const float* seg_w = (const float*)d_in[1];
  const float* seg_b = (const float*)d_in[2];
  const float* pc_w  = (const float*)d_in[3];
  const float* pc_b  = (const float*)d_in[4];
  const float* mem   = (const float*)d_in[5];
  const float* ln_g  = (const float*)d_in[6];
  const float* ln_b  = (const float*)d_in[7];
  const float* w1    = (const float*)d_in[8];
  const float* b1    = (const float*)d_in[9];
  const float* w2    = (const float*)d_in[10];
  const float* b2    = (const float*)d_in[11];

  char* ws = (char*)d_ws;
  float* pc_buf = (float*)(ws + WS_PC);
  float* s_buf  = (float*)(ws + WS_S);
  u16*   Wb     = (u16*)(ws + WS_WB);
  u16*   memFb  = (u16*)(ws + WS_MEMF);
  u16*   memTb  = (u16*)(ws + WS_MEMT);
  float* sklb   = (float*)(ws + WS_SKL);
  float* lossb  = (float*)(ws + WS_LOSS);
  float* out    = (float*)d_out;

  k_init<<<2179, 256, 0, stream>>>(seg_w, pc_w, mem, Wb, memFb, memTb, sklb, lossb);
  k_proj<<<384, 256, 0, stream>>>(feat, Wb, seg_b, pc_b, pc_buf, s_buf, out + 288);
  k_attn<<<384, 256, 0, stream>>>(pc_buf, s_buf, memFb, memTb, sklb, lossb);
  k_head<<<1, 128, 0, stream>>>(sklb, ln_g, ln_b, w1, b1, w2, b2, lossb, out);
}

// Round 3
// 449.757 us; speedup vs baseline: 1.1936x; 1.0353x over previous
//
#include <hip/hip_runtime.h>

typedef __bf16 bf16_t;
typedef bf16_t bf16x8 __attribute__((ext_vector_type(8)));
typedef float f32x4 __attribute__((ext_vector_type(4)));
typedef unsigned short u16;

#define MFMA16 __builtin_amdgcn_mfma_f32_16x16x32_bf16

#define NT_TOK   12288           // tokens per batch (L*N)
#define T_TOK    49152           // total tokens
#define NWELT    163840          // 160*1024 packed W elements
#define NMELT    196608          // 128*1536 mem elements

// workspace layout (bytes), all 16B aligned
#define WS_PC    0               // float[T_TOK*128]   pc (biased, fp32)
#define WS_S     25165824        // float[T_TOK*24]    seg softmax
#define WS_WB    29884416        // u16[160*1024]      packed seg_w|pc_w bf16
#define WS_MEMF  30212096        // u16[128*1536]      mem bf16 (row-major)
#define WS_MEMT  30605312        // u16[1536*128]      mem^T bf16
#define WS_SKL   30998528        // float[512]         per-(b,f) running max
#define WS_LOSS  31000576        // float[1]

__device__ __forceinline__ u16 f2bf(float f) {
  union { bf16_t h; u16 u; } c; c.h = (bf16_t)f; return c.u;
}

__device__ __forceinline__ void atomic_max_f32(float* a, float v) {
  if (v >= 0.f) atomicMax((int*)a, __float_as_int(v));
  else atomicMin((unsigned int*)a, (unsigned int)__float_as_int(v));
}

// ---------------- init: pack weights/mem to bf16, init reductions ----------
__global__ void k_init(const float* __restrict__ seg_w, const float* __restrict__ pc_w,
                       const float* __restrict__ mem,
                       u16* __restrict__ Wb, u16* __restrict__ memF, u16* __restrict__ memT,
                       float* __restrict__ skl, float* __restrict__ loss)
{
  int i = blockIdx.x * 256 + threadIdx.x;
  if (i < NWELT) {
    int row = i >> 10, k = i & 1023;
    float v = 0.f;
    if (row < 24) v = seg_w[(row << 10) + k];
    else if (row < 152) v = pc_w[((row - 24) << 10) + k];
    Wb[i] = f2bf(v);
  } else if ((i -= NWELT) < NMELT) {
    memF[i] = f2bf(mem[i]);
  } else if ((i -= NMELT) < NMELT) {
    int slot = i >> 7, d = i & 127;
    memT[i] = f2bf(mem[d * 1536 + slot]);
  } else if ((i -= NMELT) < 512) {
    skl[i] = -__builtin_inff();
  } else if (i == 512) {
    *loss = 0.f;
  }
}

// ------- projection: 64 tok/block, 768 blocks (3/CU), dbuf LDS W ----------
// Wl row pad = 40 u16 (80 B): rows stay 16B-aligned, bank aliasing <= 2-way.
__global__ __launch_bounds__(256, 3) void k_proj(
    const float* __restrict__ feat, const u16* __restrict__ Wb,
    const float* __restrict__ seg_b, const float* __restrict__ pc_b,
    float* __restrict__ pc_out, float* __restrict__ s_out, float* __restrict__ out_seg)
{
  __shared__ u16 Wl[2][160 * 40];
  const int tid = threadIdx.x;
  const int w = tid >> 6;
  const int lane = tid & 63;
  const int n = lane & 15;
  const int q = lane >> 4;
  const int base = blockIdx.x * 64;

  f32x4 acc[10];
  #pragma unroll
  for (int t = 0; t < 10; ++t) acc[t] = (f32x4){0.f, 0.f, 0.f, 0.f};

  const float* fp0 = feat + (size_t)(base + w * 16 + n) * 1024 + q * 8;
  const uint4* Wg4 = (const uint4*)Wb;     // 160 rows x 128 uint4 (8 bf16 each)
  const int r0 = tid >> 2, c0 = tid & 3;   // staging coords: rows r0,r0+64,(r0+128)

  // prologue: stage kc=0 into buffer 0
  uint4 s0 = Wg4[r0 * 128 + c0];
  uint4 s1 = Wg4[(64 + r0) * 128 + c0];
  uint4 s2;
  if (tid < 128) s2 = Wg4[(128 + r0) * 128 + c0];
  *(uint4*)(&Wl[0][r0 * 40 + c0 * 8]) = s0;
  *(uint4*)(&Wl[0][(64 + r0) * 40 + c0 * 8]) = s1;
  if (tid < 128) *(uint4*)(&Wl[0][(128 + r0) * 40 + c0 * 8]) = s2;
  __syncthreads();

  for (int kc = 0; kc < 32; ++kc) {
    const u16* buf = Wl[kc & 1];
    // prefetch next W chunk into registers (stays in flight across MFMAs)
    if (kc < 31) {
      const int co = (kc + 1) * 4 + c0;
      s0 = Wg4[r0 * 128 + co];
      s1 = Wg4[(64 + r0) * 128 + co];
      if (tid < 128) s2 = Wg4[(128 + r0) * 128 + co];
    }
    // feat A-frag (fp32 -> bf16 in regs)
    bf16x8 af;
    {
      const float4* a0 = (const float4*)(fp0 + kc * 32);
      float4 x0 = a0[0], y0 = a0[1];
      af[0] = (bf16_t)x0.x; af[1] = (bf16_t)x0.y; af[2] = (bf16_t)x0.z; af[3] = (bf16_t)x0.w;
      af[4] = (bf16_t)y0.x; af[5] = (bf16_t)y0.y; af[6] = (bf16_t)y0.z; af[7] = (bf16_t)y0.w;
    }
    #pragma unroll
    for (int t = 0; t < 10; ++t) {
      bf16x8 bw = *(const bf16x8*)(&buf[(t * 16 + n) * 40 + q * 8]);
      acc[t] = MFMA16(af, bw, acc[t], 0, 0, 0);
    }
    if (kc < 31) {
      u16* nb = Wl[(kc + 1) & 1];
      *(uint4*)(&nb[r0 * 40 + c0 * 8]) = s0;
      *(uint4*)(&nb[(64 + r0) * 40 + c0 * 8]) = s1;
      if (tid < 128) *(uint4*)(&nb[(128 + r0) * 40 + c0 * 8]) = s2;
    }
    __syncthreads();
  }

  // epilogue: seg softmax (cols 0..23) + biased pc (cols 24..151)
  #pragma unroll
  for (int r = 0; r < 4; ++r) {
    const int token = base + w * 16 + q * 4 + r;
    float v0 = acc[0][r] + seg_b[n];
    float v1 = (n < 8) ? (acc[1][r] + seg_b[16 + n]) : -__builtin_inff();
    float mx = fmaxf(v0, v1);
    #pragma unroll
    for (int d2 = 1; d2 < 16; d2 <<= 1) mx = fmaxf(mx, __shfl_xor(mx, d2, 16));
    float e0 = __expf(v0 - mx);
    float e1 = (n < 8) ? __expf(v1 - mx) : 0.f;
    float sm = e0 + e1;
    #pragma unroll
    for (int d2 = 1; d2 < 16; d2 <<= 1) sm += __shfl_xor(sm, d2, 16);
    float is = 1.f / sm;
    float s0v = e0 * is, s1v = e1 * is;
    s_out[(size_t)token * 24 + n] = s0v;
    if (n < 8) s_out[(size_t)token * 24 + 16 + n] = s1v;
    const int b = token / NT_TOK;
    const int rem = token - b * NT_TOK;
    const int l = rem >> 9, p = rem & 511;
    float* so = out_seg + ((size_t)(b * 24 + l) * 24) * 512 + p;
    so[(size_t)n * 512] = s0v;
    if (n < 8) so[(size_t)(16 + n) * 512] = s1v;
    #pragma unroll
    for (int t = 1; t < 10; ++t) {
      int col = t * 16 + n;
      if (col >= 24 && col < 152) {
        pc_out[(size_t)token * 128 + (col - 24)] = acc[t][r] + pc_b[col - 24];
      }
    }
  }
}

// ------- attention: 64 tok/block, 768 blocks (3/CU), S^T + padded LDS -----
#define AS_S     0                     // float[64][26]   = 6656
#define AS_MT    6656                  // u16[64][136]    = 17408
#define AS_MF    24064                 // u16[128][72]    = 18432
#define AS_P     42496                 // u16[4][16][72]  = 9216 (wave-private)
#define AS_RS    51712                 // float[4][128]   = 2048
#define AS_RL    53760                 // float[4]
#define AS_TOT   53776

__global__ __launch_bounds__(256, 3) void k_attn(
    const float* __restrict__ pc, const float* __restrict__ s_in,
    const u16* __restrict__ memF, const u16* __restrict__ memT,
    float* __restrict__ skl, float* __restrict__ loss)
{
  __shared__ __align__(16) char smem[AS_TOT];
  float* s_tile = (float*)(smem + AS_S);        // [64][26] padded
  u16* mTl = (u16*)(smem + AS_MT);              // [64 slots][136]
  u16* mFl = (u16*)(smem + AS_MF);              // [128 f][72]
  u16* Pl  = (u16*)(smem + AS_P);               // per-wave [16 tok][72]
  float* redS = (float*)(smem + AS_RS);
  float* redL = (float*)(smem + AS_RL);

  const int tid = threadIdx.x;
  const int w = tid >> 6, lane = tid & 63, n = lane & 15, q = lane >> 4;
  const int base = blockIdx.x * 64;
  const int wreg = w * 16 * 72;

  for (int i = tid; i < 1536; i += 256) {
    int t = i / 24, jj = i - t * 24;
    s_tile[t * 26 + jj] = s_in[(size_t)base * 24 + i];
  }

  // Q fragments straight from global pc (fp32 -> bf16 in regs); 16 tok/wave
  bf16x8 qf[4];
  #pragma unroll
  for (int ks = 0; ks < 4; ++ks) {
    const float4* qp = (const float4*)(pc + (size_t)(base + w * 16 + n) * 128 + ks * 32 + q * 8);
    float4 x = qp[0], y = qp[1];
    bf16x8 a;
    a[0] = (bf16_t)x.x; a[1] = (bf16_t)x.y; a[2] = (bf16_t)x.z; a[3] = (bf16_t)x.w;
    a[4] = (bf16_t)y.x; a[5] = (bf16_t)y.y; a[6] = (bf16_t)y.z; a[7] = (bf16_t)y.w;
    qf[ks] = a;
  }

  f32x4 o[8];
  #pragma unroll
  for (int fj = 0; fj < 8; ++fj) o[fj] = (f32x4){0.f, 0.f, 0.f, 0.f};
  float m_run = -__builtin_inff();
  float l_run = 0.f;

  const float invs = 0.088388347648318447f; // 1/sqrt(128)

  for (int j = 0; j < 24; ++j) {
    __syncthreads();   // previous iteration's readers done before restage
    {
      const uint4* gT = (const uint4*)memT;
      const uint4* gF = (const uint4*)memF;
      #pragma unroll
      for (int it = 0; it < 4; ++it) {
        int idx = tid + it * 256;
        int slot = idx >> 4, c = idx & 15;
        *(uint4*)(&mTl[slot * 136 + c * 8]) = gT[(size_t)(j * 64 + slot) * 16 + c];
      }
      #pragma unroll
      for (int it = 0; it < 4; ++it) {
        int idx = tid + it * 256;
        int f = idx >> 3, s8 = idx & 7;
        *(uint4*)(&mFl[f * 72 + s8 * 8]) = gF[(size_t)f * 192 + j * 8 + s8];
      }
    }
    __syncthreads();

    // S^T = memChunk . Q^T : A = mT frags (slot rows), B = qf (token cols)
    f32x4 sacc[4];
    #pragma unroll
    for (int st = 0; st < 4; ++st) sacc[st] = (f32x4){0.f, 0.f, 0.f, 0.f};
    #pragma unroll
    for (int ks = 0; ks < 4; ++ks) {
      #pragma unroll
      for (int st = 0; st < 4; ++st) {
        bf16x8 am = *(const bf16x8*)(&mTl[(st * 16 + n) * 136 + ks * 32 + q * 8]);
        sacc[st] = MFMA16(am, qf[ks], sacc[st], 0, 0, 0);
      }
    }

    // online softmax: lane (n,q) holds token n, slots st*16+q*4+r
    {
      float sj = s_tile[(w * 16 + n) * 26 + j] * invs;
      float lv[4][4];
      float cm = -__builtin_inff();
      #pragma unroll
      for (int st = 0; st < 4; ++st)
        #pragma unroll
        for (int r = 0; r < 4; ++r) {
          lv[st][r] = sacc[st][r] * sj;
          cm = fmaxf(cm, lv[st][r]);
        }
      cm = fmaxf(cm, __shfl_xor(cm, 16, 64));
      cm = fmaxf(cm, __shfl_xor(cm, 32, 64));
      float mnew = fmaxf(m_run, cm);
      float alpha = __expf(m_run - mnew);
      m_run = mnew;
      float rs = 0.f;
      #pragma unroll
      for (int st = 0; st < 4; ++st) {
        float p0 = __expf(lv[st][0] - mnew);
        float p1 = __expf(lv[st][1] - mnew);
        float p2 = __expf(lv[st][2] - mnew);
        float p3 = __expf(lv[st][3] - mnew);
        rs += (p0 + p1) + (p2 + p3);
        ushort4 pk;
        pk.x = f2bf(p0); pk.y = f2bf(p1); pk.z = f2bf(p2); pk.w = f2bf(p3);
        *(ushort4*)(&Pl[wreg + n * 72 + st * 16 + q * 4]) = pk;
      }
      rs += __shfl_xor(rs, 16, 64);
      rs += __shfl_xor(rs, 32, 64);
      l_run = l_run * alpha + rs;
      f32x4 av;
      av[0] = __shfl(alpha, q * 4 + 0, 64);
      av[1] = __shfl(alpha, q * 4 + 1, 64);
      av[2] = __shfl(alpha, q * 4 + 2, 64);
      av[3] = __shfl(alpha, q * 4 + 3, 64);
      #pragma unroll
      for (int fj = 0; fj < 8; ++fj) o[fj] *= av;
    }

    // O += P . memF^T (Pl wave-private: per-wave LDS ops in order, no barrier)
    #pragma unroll
    for (int h = 0; h < 2; ++h) {
      bf16x8 pa = *(const bf16x8*)(&Pl[wreg + n * 72 + h * 32 + q * 8]);
      #pragma unroll
      for (int fj = 0; fj < 8; ++fj) {
        bf16x8 bb = *(const bf16x8*)(&mFl[(fj * 16 + n) * 72 + h * 32 + q * 8]);
        o[fj] = MFMA16(pa, bb, o[fj], 0, 0, 0);
      }
    }
  }

  // finalize: rec = O/l, loss partial, per-f max
  float lsum = 0.f;
  float fmax8[8];
  #pragma unroll
  for (int fj = 0; fj < 8; ++fj) fmax8[fj] = -__builtin_inff();
  {
    f32x4 linv;
    #pragma unroll
    for (int r = 0; r < 4; ++r) linv[r] = 1.f / __shfl(l_run, q * 4 + r, 64);
    #pragma unroll
    for (int fj = 0; fj < 8; ++fj)
      #pragma unroll
      for (int r = 0; r < 4; ++r) {
        const int token = base + w * 16 + q * 4 + r;
        float rec = o[fj][r] * linv[r];
        float d = rec - pc[(size_t)token * 128 + fj * 16 + n];
        lsum += d * d;
        fmax8[fj] = fmaxf(fmax8[fj], rec);
      }
  }
  #pragma unroll
  for (int fj = 0; fj < 8; ++fj) {
    float v = fmax8[fj];
    v = fmaxf(v, __shfl_xor(v, 16, 64));
    v = fmaxf(v, __shfl_xor(v, 32, 64));
    fmax8[fj] = v;
  }
  #pragma unroll
  for (int d2 = 1; d2 < 64; d2 <<= 1) lsum += __shfl_xor(lsum, d2, 64);
  if (q == 0) {
    #pragma unroll
    for (int fj = 0; fj < 8; ++fj) redS[w * 128 + fj * 16 + n] = fmax8[fj];
  }
  if (lane == 0) redL[w] = lsum;
  __syncthreads();
  if (tid < 128) {
    float v = fmaxf(fmaxf(redS[tid], redS[128 + tid]), fmaxf(redS[256 + tid], redS[384 + tid]));
    atomic_max_f32(&skl[(base / NT_TOK) * 128 + tid], v);
  }
  if (tid == 0) atomicAdd(loss, redL[0] + redL[1] + redL[2] + redL[3]);
}

// ---------------- head: LN -> Linear -> GELU -> Linear + loss finalize -----
__global__ void k_head(const float* __restrict__ skl,
                       const float* __restrict__ ln_g, const float* __restrict__ ln_b,
                       const float* __restrict__ w1, const float* __restrict__ b1,
                       const float* __restrict__ w2, const float* __restrict__ b2,
                       const float* __restrict__ loss, float* __restrict__ out)
{
  __shared__ float hbuf[128];
  __shared__ float gbuf[64];
  __shared__ float red[4];
  const int t = threadIdx.x;            // 128 threads
  const int ln = t & 63, wv = t >> 6;
  for (int b = 0; b < 4; ++b) {
    float x = skl[b * 128 + t];
    float s1 = x, s2 = x * x;
    #pragma unroll
    for (int d = 1; d < 64; d <<= 1) {
      s1 += __shfl_xor(s1, d, 64);
      s2 += __shfl_xor(s2, d, 64);
    }
    if (ln == 0) { red[wv * 2] = s1; red[wv * 2 + 1] = s2; }
    __syncthreads();
    float mu = (red[0] + red[2]) * (1.f / 128.f);
    float var = (red[1] + red[3]) * (1.f / 128.f) - mu * mu;
    float hn = (x - mu) * rsqrtf(var + 1e-5f) * ln_g[t] + ln_b[t];
    hbuf[t] = hn;
    __syncthreads();
    if (t < 64) {
      float a = b1[t];
      for (int c = 0; c < 128; ++c) a += hbuf[c] * w1[t * 128 + c];
      gbuf[t] = 0.5f * a * (1.f + erff(a * 0.70710678118654752f));
    }
    __syncthreads();
    if (t < 72) {
      float a = b2[t];
      for (int c = 0; c < 64; ++c) a += gbuf[c] * w2[t * 64 + c];
      out[b * 72 + t] = a;
    }
    __syncthreads();
  }
  if (t == 0) out[1179936] = loss[0] * (1.f / 6291456.f);
}

extern "C" void kernel_launch(void* const* d_in, const int* in_sizes, int n_in,
                              void* d_out, int out_size, void* d_ws, size_t ws_size,
                              hipStream_t stream) {
  (void)in_sizes; (void)n_in; (void)out_size; (void)ws_size;
  const float* feat  = (const float*)d_in[0];
  const float* seg_w = (const float*)d_in[1];
  const float* seg_b = (const float*)d_in[2];
  const float* pc_w  = (const float*)d_in[3];
  const float* pc_b  = (const float*)d_in[4];
  const float* mem   = (const float*)d_in[5];
  const float* ln_g  = (const float*)d_in[6];
  const float* ln_b  = (const float*)d_in[7];
  const float* w1    = (const float*)d_in[8];
  const float* b1    = (const float*)d_in[9];
  const float* w2    = (const float*)d_in[10];
  const float* b2    = (const float*)d_in[11];

  char* ws = (char*)d_ws;
  float* pc_buf = (float*)(ws + WS_PC);
  float* s_buf  = (float*)(ws + WS_S);
  u16*   Wb     = (u16*)(ws + WS_WB);
  u16*   memFb  = (u16*)(ws + WS_MEMF);
  u16*   memTb  = (u16*)(ws + WS_MEMT);
  float* sklb   = (float*)(ws + WS_SKL);
  float* lossb  = (float*)(ws + WS_LOSS);
  float* out    = (float*)d_out;

  k_init<<<2179, 256, 0, stream>>>(seg_w, pc_w, mem, Wb, memFb, memTb, sklb, lossb);
  k_proj<<<768, 256, 0, stream>>>(feat, Wb, seg_b, pc_b, pc_buf, s_buf, out + 288);
  k_attn<<<768, 256, 0, stream>>>(pc_buf, s_buf, memFb, memTb, sklb, lossb);
  k_head<<<1, 128, 0, stream>>>(sklb, ln_g, ln_b, w1, b1, w2, b2, lossb, out);
}